// Round 2
// baseline (555.599 us; speedup 1.0000x reference)
//
#include <hip/hip_runtime.h>
#include <hip/hip_cooperative_groups.h>
#include <math.h>

namespace cg = cooperative_groups;

#define BB 64
#define FF 128
#define TT 4096
#define KK 13
#define NT (BB * TT)          // 262144 columns = mcd sample count
#define NBLK 1024             // 4 blocks/CU -> cooperative co-residency needs VGPR<=128
#define MCD_C  6.14185100f    // (10/ln10)*sqrt(2)

// Scale note: CMVN divides each k by its own std, so the per-k DCT norm and
// the ln2 of log1p == ln2*log2 cancel exactly; we accumulate raw log2-based
// unscaled coefficients (epsilon placement shifts output ~1e-5, far under
// threshold). ws layout: 52 stat accumulators, each on its own 64B line.

// ---------------- wave reduction on the VALU pipe (DPP) ----------------
// Canonical gfx9 wave64 sum; lane 63 ends with the full 64-lane total.
template <int CTRL>
__device__ __forceinline__ float dpp_add(float x) {
    return x + __int_as_float(__builtin_amdgcn_update_dpp(
                   0, __float_as_int(x), CTRL, 0xf, 0xf, true));
}
__device__ __forceinline__ float wave_sum(float x) {
    x = dpp_add<0x111>(x);   // row_shr:1
    x = dpp_add<0x112>(x);   // row_shr:2
    x = dpp_add<0x114>(x);   // row_shr:4
    x = dpp_add<0x118>(x);   // row_shr:8  -> lane 15 of each row = row sum
    x = dpp_add<0x142>(x);   // row_bcast:15
    x = dpp_add<0x143>(x);   // row_bcast:31 -> lane 63 = total
    return x;
}

// Agent-scope load: per-XCD L2s are not coherent; force the read to the
// device-coherent point when consuming cross-block atomics.
__device__ __forceinline__ float agent_load(const float* p) {
    return __hip_atomic_load(p, __ATOMIC_RELAXED, __HIP_MEMORY_SCOPE_AGENT);
}

// ---------------- shared accumulation body ----------------
__device__ __forceinline__ void load8(const float* __restrict__ p, int f0,
                                      float (&v)[8]) {
#pragma unroll
    for (int j = 0; j < 8; ++j) v[j] = p[(size_t)(f0 + j) * TT];
}

__device__ __forceinline__ void comp8(int f0, const float (&vT)[8],
                                      const float (&vP)[8],
                                      float (&aT)[KK], float (&aP)[KK]) {
#pragma unroll
    for (int j = 0; j < 8; ++j) {
        const float xT = __log2f(1.0f + fabsf(vT[j]));
        const float xP = __log2f(1.0f + fabsf(vP[j]));
        // Chebyshev recurrence: bk[k] = cos(k * pi*(f+0.5)/128); all indices
        // compile-time (full unroll) so bk[] stays in registers.
        float bk[KK];
        bk[0] = 1.0f;
        bk[1] = __cosf((3.14159265358979f / 128.0f) * ((float)(f0 + j) + 0.5f));
        const float tw = bk[1] + bk[1];
#pragma unroll
        for (int k = 2; k < KK; ++k) bk[k] = fmaf(tw, bk[k - 1], -bk[k - 2]);
#pragma unroll
        for (int k = 0; k < KK; ++k) {
            aT[k] = fmaf(bk[k], xT, aT[k]);
            aP[k] = fmaf(bk[k], xP, aP[k]);
        }
    }
}

// One column of BOTH tensors -> 26 unscaled coefficients in registers.
// Explicit 2-deep pipeline with NAMED buffers (static indexing only): loads
// of batch i+1 are in flight while batch i computes.
__device__ __forceinline__ void accum_col(const float* __restrict__ pT,
                                          const float* __restrict__ pP,
                                          float (&aT)[KK], float (&aP)[KK]) {
#pragma unroll
    for (int k = 0; k < KK; ++k) { aT[k] = 0.0f; aP[k] = 0.0f; }
    float vT0[8], vP0[8], vT1[8], vP1[8];
    load8(pT, 0, vT0); load8(pP, 0, vP0);
#pragma unroll 1
    for (int f0 = 0; f0 < FF - 16; f0 += 16) {
        load8(pT, f0 + 8, vT1);  load8(pP, f0 + 8, vP1);
        comp8(f0, vT0, vP0, aT, aP);
        load8(pT, f0 + 16, vT0); load8(pP, f0 + 16, vP0);
        comp8(f0 + 8, vT1, vP1, aT, aP);
    }
    load8(pT, FF - 8, vT1); load8(pP, FF - 8, vP1);
    comp8(FF - 16, vT0, vP0, aT, aP);
    comp8(FF - 8, vT1, vP1, aT, aP);
}

// Per-block stat reduction -> device atomics. Layout j in [0,52):
// [T sums 0-12 | T sumsq 13-25 | P sums 26-38 | P sumsq 39-51], 64B line each.
__device__ __forceinline__ void block_stats(const float (&aT)[KK],
                                            const float (&aP)[KK],
                                            int tid, float* __restrict__ sums) {
    const int lane = tid & 63;
    const int wave = tid >> 6;
    __shared__ float red[4][52];
#pragma unroll
    for (int k = 0; k < KK; ++k) {
        const float s0 = wave_sum(aT[k]);
        const float s1 = wave_sum(aT[k] * aT[k]);
        const float s2 = wave_sum(aP[k]);
        const float s3 = wave_sum(aP[k] * aP[k]);
        if (lane == 63) {
            red[wave][k]      = s0; red[wave][13 + k] = s1;
            red[wave][26 + k] = s2; red[wave][39 + k] = s3;
        }
    }
    __syncthreads();
    if (tid < 52) {
        const float v = red[0][tid] + red[1][tid] + red[2][tid] + red[3][tid];
        atomicAdd(&sums[tid * 16], v);
    }
}

// Finalize mean / 1/(std+1e-6) (ddof=1) into caller's LDS.
__device__ __forceinline__ void finalize_stats(int tid,
                                               const float* __restrict__ sums,
                                               float (&mS)[2][KK],
                                               float (&iS)[2][KK]) {
    if (tid < 26) {
        const int tns = tid >= 13;
        const int k   = tid - tns * 13;
        const float s = agent_load(&sums[(tns * 26 + k) * 16]);
        const float q = agent_load(&sums[(tns * 26 + 13 + k) * 16]);
        const float N = (float)NT;
        const float m = s / N;
        const float var = fmaxf((q - s * m) / (N - 1.0f), 0.0f);
        mS[tns][k] = m;
        iS[tns][k] = 1.0f / (sqrtf(var) + 1e-6f);
    }
    __syncthreads();
}

// Per-column mcd from register coefficients -> block sum -> atomicAdd(out).
__device__ __forceinline__ void mcd_epilogue(const float (&aT)[KK],
                                             const float (&aP)[KK],
                                             int tid, const float (&mS)[2][KK],
                                             const float (&iS)[2][KK],
                                             float* __restrict__ out) {
    float ss = 0.0f;
#pragma unroll
    for (int k = 0; k < KK; ++k) {
        const float d = (aT[k] - mS[0][k]) * iS[0][k]
                      - (aP[k] - mS[1][k]) * iS[1][k];
        ss = fmaf(d, d, ss);
    }
    float v = wave_sum(MCD_C * sqrtf(ss));
    const int lane = tid & 63;
    const int wave = tid >> 6;
    __shared__ float r2[4];
    if (lane == 63) r2[wave] = v;
    __syncthreads();
    if (tid == 0)
        atomicAdd(out, (r2[0] + r2[1] + r2[2] + r2[3]) * (1.0f / (float)NT));
}

// ---------------- primary: ONE cooperative kernel ----------------
__global__ __launch_bounds__(256)
__attribute__((amdgpu_waves_per_eu(4)))   // min 4 waves/EU -> VGPR<=128 ->
                                          // 4 blocks/CU, validates 1024-block
                                          // cooperative launch with margin
void mcd_fused(const float* __restrict__ melT, const float* __restrict__ melP,
               float* __restrict__ sums, float* __restrict__ out)
{
    const int tid = threadIdx.x;
    const int col = blockIdx.x * 256 + tid;            // [0, NT)
    const int b   = col >> 12;                         // / TT
    const int t   = col & (TT - 1);
    const size_t base = (size_t)b * (size_t)(FF * TT) + (size_t)t;

    float aT[KK], aP[KK];
    accum_col(melT + base, melP + base, aT, aP);
    block_stats(aT, aP, tid, sums);

    __threadfence();              // drain device-scope adds before the barrier
    cg::this_grid().sync();

    __shared__ float mS[2][KK], iS[2][KK];
    finalize_stats(tid, sums, mS, iS);
    mcd_epilogue(aT, aP, tid, mS, iS, out);
}

// ---------------- fallback: 2-pass recompute (no grid barrier) ----------------
__global__ __launch_bounds__(256)
__attribute__((amdgpu_waves_per_eu(4)))
void stats_kernel(const float* __restrict__ melT, const float* __restrict__ melP,
                  float* __restrict__ sums)
{
    const int tid = threadIdx.x;
    const int col = blockIdx.x * 256 + tid;
    const int b   = col >> 12;
    const int t   = col & (TT - 1);
    const size_t base = (size_t)b * (size_t)(FF * TT) + (size_t)t;
    float aT[KK], aP[KK];
    accum_col(melT + base, melP + base, aT, aP);
    block_stats(aT, aP, tid, sums);
}

__global__ __launch_bounds__(256)
__attribute__((amdgpu_waves_per_eu(4)))
void final_kernel(const float* __restrict__ melT, const float* __restrict__ melP,
                  const float* __restrict__ sums, float* __restrict__ out)
{
    const int tid = threadIdx.x;
    const int col = blockIdx.x * 256 + tid;
    const int b   = col >> 12;
    const int t   = col & (TT - 1);
    const size_t base = (size_t)b * (size_t)(FF * TT) + (size_t)t;
    float aT[KK], aP[KK];
    accum_col(melT + base, melP + base, aT, aP);
    __shared__ float mS[2][KK], iS[2][KK];
    finalize_stats(tid, sums, mS, iS);
    mcd_epilogue(aT, aP, tid, mS, iS, out);
}

extern "C" void kernel_launch(void* const* d_in, const int* in_sizes, int n_in,
                              void* d_out, int out_size, void* d_ws, size_t ws_size,
                              hipStream_t stream) {
    const float* melT = (const float*)d_in[0];
    const float* melP = (const float*)d_in[1];
    float* sums = (float*)d_ws;
    float* out  = (float*)d_out;

    hipMemsetAsync(d_ws, 0, 4096, stream);            // zero stat accumulators
    hipMemsetAsync(d_out, 0, sizeof(float), stream);  // out accumulates atomically

    void* args[] = { (void*)&melT, (void*)&melP, (void*)&sums, (void*)&out };
    hipError_t err = hipLaunchCooperativeKernel(
        (const void*)mcd_fused, dim3(NBLK), dim3(256), args, 0, stream);
    if (err != hipSuccess) {
        (void)hipGetLastError();   // clear last-error state
        // Correct (slower) path: recompute coefficients in a second pass.
        stats_kernel<<<NBLK, 256, 0, stream>>>(melT, melP, sums);
        final_kernel<<<NBLK, 256, 0, stream>>>(melT, melP, sums, out);
    }
}

// Round 3
// 309.398 us; speedup vs baseline: 1.7957x; 1.7957x over previous
//
#include <hip/hip_runtime.h>
#include <math.h>

#define BB 64
#define FF 128
#define TT 4096
#define KK 13
#define NT (BB * TT)          // 262144 columns per tensor (= mcd sample count)
#define NPAIR (NT / 2)        // 131072 column-pairs per tensor
#define MCD_C  6.14185100f    // (10/ln10)*sqrt(2)

// Scale note: CMVN divides each k by its own std, so the per-k DCT norm and
// the ln2 of log1p == ln2*log2 cancel exactly; we accumulate raw log2-based
// unscaled coefficients (epsilon placement shifts output ~1e-5, far under
// threshold).
//
// ws layout (bytes):
//   [0,    4096)  : 52 stat accumulators, each on its own 64B line
//   [8192, ...)   : cT planes (13*NT floats), then cP planes (13*NT floats)
//
// Pass 1 (the round-0 winner, rebalanced for occupancy): 2048 blocks
// (8 blocks/CU -> 32 waves/CU, 2x round 0). Thread = one column-PAIR of one
// tensor, HALF the f-planes: lanes 0-31 accumulate f in [0,64), lanes 32-63
// f in [64,128). Halves merged with shfl_xor(32) before stats/stores.
// Register budget ~58 (26 acc + 16 buffer + chain) -> fits the 64-VGPR cap
// that waves_per_eu(8,8) pins, so 8 waves/EU is achievable, not aspirational.
// (Round-2 lesson: min-only waves_per_eu let the allocator clamp a 100-reg
// body to 64 and serialize everything. Pin BOTH bounds, size body to fit.)

#define KLIST(X) X(0) X(1) X(2) X(3) X(4) X(5) X(6) X(7) X(8) X(9) X(10) X(11) X(12)
#define K12(X)        X(1) X(2) X(3) X(4) X(5) X(6) X(7) X(8) X(9) X(10) X(11) X(12)

// Wave64 sum on the VALU pipe (DPP) — validated for correctness in round 2.
// Lane 63 ends with the full 64-lane total.
template <int CTRL>
__device__ __forceinline__ float dpp_add(float x) {
    return x + __int_as_float(__builtin_amdgcn_update_dpp(
                   0, __float_as_int(x), CTRL, 0xf, 0xf, true));
}
__device__ __forceinline__ float wave_sum(float x) {
    x = dpp_add<0x111>(x);   // row_shr:1
    x = dpp_add<0x112>(x);   // row_shr:2
    x = dpp_add<0x114>(x);   // row_shr:4
    x = dpp_add<0x118>(x);   // row_shr:8  -> lane 15 of each row = row sum
    x = dpp_add<0x142>(x);   // row_bcast:15
    x = dpp_add<0x143>(x);   // row_bcast:31 -> lane 63 = total
    return x;
}

__global__ __launch_bounds__(256)
__attribute__((amdgpu_waves_per_eu(8, 8)))
void pass1_kernel(
    const float* __restrict__ melT, const float* __restrict__ melP,
    float* __restrict__ sums, float* __restrict__ cT, float* __restrict__ cP)
{
    const int tensor = blockIdx.x >> 10;                  // 0=true 1=pred
    const int tid  = threadIdx.x;
    const int lane = tid & 63;
    const int wave = tid >> 6;
    const int half = lane >> 5;                           // f-half owned
    // 32 column-pairs per half-wave; 128 pairs per block
    const int gp = (blockIdx.x & 1023) * 128 + wave * 32 + (lane & 31);
    const float* __restrict__ src = tensor ? melP : melT;
    float* __restrict__ dst = tensor ? cP : cT;

    const int g0 = gp << 1;          // first column index
    const int b  = g0 >> 12;         // / TT
    const int t0 = g0 & (TT - 1);    // even
    const int fbase = half << 6;     // 0 or 64
    const float* p = src + (size_t)b * (FF * TT) + (size_t)fbase * TT + t0;

#define DECLACC(i) float ax##i = 0.f, ay##i = 0.f;
    KLIST(DECLACC)
#undef DECLACC

    for (int f0 = 0; f0 < 64; f0 += 8) {
        // 8 independent float2 loads in flight; each instruction covers two
        // 256B segments (planes f and f+64 for the two half-waves)
        float2 v[8];
#pragma unroll
        for (int j = 0; j < 8; ++j)
            v[j] = *(const float2*)(p + (size_t)(f0 + j) * TT);

#pragma unroll
        for (int j = 0; j < 8; ++j) {
            const float xx = __log2f(1.0f + fabsf(v[j].x));
            const float xy = __log2f(1.0f + fabsf(v[j].y));

            // Chebyshev recurrence: b_k = cos(k*pi*(f+0.5)/128); 8 independent
            // chains (one per j) give the scheduler ILP.
            const float b1 = __cosf((3.14159265358979f / 128.0f) *
                                    ((float)(fbase + f0 + j) + 0.5f));
            const float tw = b1 + b1;
            const float b2  = fmaf(tw, b1,  -1.0f);
            const float b3  = fmaf(tw, b2,  -b1);
            const float b4  = fmaf(tw, b3,  -b2);
            const float b5  = fmaf(tw, b4,  -b3);
            const float b6  = fmaf(tw, b5,  -b4);
            const float b7  = fmaf(tw, b6,  -b5);
            const float b8  = fmaf(tw, b7,  -b6);
            const float b9  = fmaf(tw, b8,  -b7);
            const float b10 = fmaf(tw, b9,  -b8);
            const float b11 = fmaf(tw, b10, -b9);
            const float b12 = fmaf(tw, b11, -b10);

            ax0 += xx; ay0 += xy;
#define FMAK(i) ax##i = fmaf(b##i, xx, ax##i); ay##i = fmaf(b##i, xy, ay##i);
            K12(FMAK)
#undef FMAK
        }
    }

    // Merge f-halves: afterwards lanes l and l^32 hold identical full coeffs.
#define MRG(i) ax##i += __shfl_xor(ax##i, 32); ay##i += __shfl_xor(ay##i, 32);
    KLIST(MRG)
#undef MRG

    // Cache unscaled cepstra: plane k, float2 per pair, stored once (half 0).
    if (half == 0) {
#define STK(i) ((float2*)(dst + (size_t)(i) * NT))[gp] = make_float2(ax##i, ay##i);
        KLIST(STK)
#undef STK
    }

    // Stats: sum & sumsq of the FULL (merged) coefficients. Every pair is
    // duplicated across 2 lanes -> scale by 0.5 at the atomic.
    __shared__ float red[4][26];
#define REDK(i) { \
        float s = wave_sum(ax##i + ay##i); \
        float q = wave_sum(fmaf(ax##i, ax##i, ay##i * ay##i)); \
        if (lane == 63) { red[wave][i] = s; red[wave][13 + i] = q; } }
    KLIST(REDK)
#undef REDK
    __syncthreads();
    if (tid < 26) {
        const float v = red[0][tid] + red[1][tid] + red[2][tid] + red[3][tid];
        atomicAdd(&sums[(tensor * 26 + tid) * 16], 0.5f * v);  // own 64B line
    }
}

// Pass 2: finalize mean / 1/(std+1e-6) (ddof=1) in LDS, stream cached
// cepstra (54 MB, L3-hot), per-column mcd, block sum -> atomicAdd(out).
// 1024 blocks -> 16 waves/CU (2x round 0's pass2). Absorbs old pass3.
__global__ __launch_bounds__(256) void pass2_kernel(
    const float* __restrict__ sums, const float* __restrict__ cT,
    const float* __restrict__ cP, float* __restrict__ out)
{
    __shared__ float mS[2][13], iS[2][13];
    if (threadIdx.x < 26) {
        const int tns = threadIdx.x >= 13;
        const int k   = threadIdx.x - tns * 13;
        const float s = sums[(tns * 26 + k) * 16];
        const float q = sums[(tns * 26 + 13 + k) * 16];
        const float N = (float)NT;
        const float m = s / N;
        const float var = fmaxf((q - s * m) / (N - 1.0f), 0.0f);
        mS[tns][k] = m;
        iS[tns][k] = 1.0f / (sqrtf(var) + 1e-6f);
    }
    __syncthreads();

    const int col = blockIdx.x * 256 + threadIdx.x;   // [0, NT)
    float ss = 0.0f;
#pragma unroll
    for (int k = 0; k < KK; ++k) {
        const float a = cT[(size_t)k * NT + col];
        const float p = cP[(size_t)k * NT + col];
        const float d = (a - mS[0][k]) * iS[0][k] - (p - mS[1][k]) * iS[1][k];
        ss = fmaf(d, d, ss);
    }
    float v = wave_sum(MCD_C * sqrtf(ss));

    const int lane = threadIdx.x & 63;
    const int wave = threadIdx.x >> 6;
    __shared__ float r2[4];
    if (lane == 63) r2[wave] = v;
    __syncthreads();
    if (threadIdx.x == 0)
        atomicAdd(out, (r2[0] + r2[1] + r2[2] + r2[3]) * (1.0f / (float)NT));
}

extern "C" void kernel_launch(void* const* d_in, const int* in_sizes, int n_in,
                              void* d_out, int out_size, void* d_ws, size_t ws_size,
                              hipStream_t stream) {
    const float* melT = (const float*)d_in[0];
    const float* melP = (const float*)d_in[1];
    float* out  = (float*)d_out;
    float* sums = (float*)d_ws;                     // padded stats
    float* cT   = (float*)((char*)d_ws + 8192);     // 13*NT floats
    float* cP   = cT + (size_t)KK * NT;             // 13*NT floats

    hipMemsetAsync(d_ws, 0, 4096, stream);          // zero stat accumulators
    hipMemsetAsync(d_out, 0, sizeof(float), stream);// out accumulates atomically

    pass1_kernel<<<2048, 256, 0, stream>>>(melT, melP, sums, cT, cP);
    pass2_kernel<<<1024, 256, 0, stream>>>(sums, cT, cP, out);
}

// Round 4
// 307.924 us; speedup vs baseline: 1.8043x; 1.0048x over previous
//
#include <hip/hip_runtime.h>
#include <math.h>

#define BB 64
#define FF 128
#define TT 4096
#define KK 13
#define NT (BB * TT)          // 262144 columns per tensor (= mcd sample count)
#define MCD_C  6.14185100f    // (10/ln10)*sqrt(2)

#define CPB 1024              // columns per block
#define CPT 4                 // columns per thread (float4 lane width)
#define PPB 4                 // planes per batch
#define NBATCH (FF / PPB)     // 32 batches
#define RING 4                // LDS ring slots (batches)

// Scale note: CMVN divides each k by its own std, so the per-k DCT norm and
// the ln2 of log1p == ln2*log2 cancel exactly; we accumulate raw log2-based
// unscaled coefficients (epsilon placement shifts output ~1e-5, far under
// threshold).
//
// ws layout (bytes):
//   [0,    4096)  : 52 stat accumulators, each on its own 64B line
//   [8192, ...)   : cT planes (13*NT floats), then cP planes (13*NT floats)
//
// R3 lesson: pass1 pins at 114 us (2.35 TB/s effective) across occupancy
// 36->58% and VGPR 64->32 -> not latency/wave-bound; the memory PATTERN or
// outstanding-depth is the cap. This version: async global_load_lds staging
// into a 4-deep LDS ring with COUNTED vmcnt (never 0 in the main loop), so
// 12 plane-loads (48 KB) stay in flight per wave independent of VGPRs, and
// each block reads 4 KB contiguous per plane.

#define KLIST(X) X(0) X(1) X(2) X(3) X(4) X(5) X(6) X(7) X(8) X(9) X(10) X(11) X(12)

// Wave64 sum on the VALU pipe (DPP); lane 63 ends with the full total.
template <int CTRL>
__device__ __forceinline__ float dpp_add(float x) {
    return x + __int_as_float(__builtin_amdgcn_update_dpp(
                   0, __float_as_int(x), CTRL, 0xf, 0xf, true));
}
__device__ __forceinline__ float wave_sum(float x) {
    x = dpp_add<0x111>(x);   // row_shr:1
    x = dpp_add<0x112>(x);   // row_shr:2
    x = dpp_add<0x114>(x);   // row_shr:4
    x = dpp_add<0x118>(x);   // row_shr:8
    x = dpp_add<0x142>(x);   // row_bcast:15
    x = dpp_add<0x143>(x);   // row_bcast:31 -> lane 63 = total
    return x;
}

// Async global->LDS, 16B per lane. LDS dest is wave-uniform base + lane*16;
// global src is per-lane. vmcnt-tracked.
__device__ __forceinline__ void gload_lds16(const float* g, float* l) {
    __builtin_amdgcn_global_load_lds(
        (const __attribute__((address_space(1))) void*)g,
        (__attribute__((address_space(3))) void*)l, 16, 0, 0);
}

template <int N>
__device__ __forceinline__ void wait_vm() {
    asm volatile("s_waitcnt vmcnt(%0)" :: "n"(N) : "memory");
}

__global__ __launch_bounds__(256)
__attribute__((amdgpu_waves_per_eu(2, 2)))   // LDS caps 2 blocks/CU = 2 waves/EU;
                                             // pinning BOTH bounds stops the
                                             // allocator clamping VGPRs (R3: 32!)
void pass1_kernel(
    const float* __restrict__ melT, const float* __restrict__ melP,
    float* __restrict__ sums, float* __restrict__ cT, float* __restrict__ cP)
{
    __shared__ float ring[RING][PPB][CPB];    // 64 KB staging ring
    __shared__ float red[4][26];

    const int tid  = threadIdx.x;
    const int lane = tid & 63;
    const int wave = tid >> 6;

    const int tensor = blockIdx.x >> 8;              // 0=true 1=pred
    const int idx    = blockIdx.x & 255;             // 64 b x 4 t-quarters
    const int b      = idx >> 2;
    const int t0     = (idx & 3) * CPB;

    const float* __restrict__ src = tensor ? melP : melT;
    float* __restrict__ dst = tensor ? cP : cT;

    // per-lane global src for this wave's 1KB quarter of each 4KB plane-chunk
    const float* gsrc = src + (size_t)b * (FF * TT) + t0 + wave * 256 + lane * 4;

    float ac[KK][CPT];
#pragma unroll
    for (int k = 0; k < KK; ++k)
#pragma unroll
        for (int c = 0; c < CPT; ++c) ac[k][c] = 0.0f;

    auto issue_batch = [&](int bt) {
        const int slot = bt & (RING - 1);
#pragma unroll
        for (int pl = 0; pl < PPB; ++pl) {
            const int f = bt * PPB + pl;
            gload_lds16(gsrc + (size_t)f * TT, &ring[slot][pl][wave * 256]);
        }
    };

    auto compute_batch = [&](int bt) {
        const int slot = bt & (RING - 1);
#pragma unroll
        for (int pl = 0; pl < PPB; ++pl) {
            const int f = bt * PPB + pl;
            const float4 v = *(const float4*)&ring[slot][pl][tid * 4];
            // Chebyshev recurrence: bk[k] = cos(k*pi*(f+0.5)/128)
            float bk[KK];
            bk[0] = 1.0f;
            bk[1] = __cosf((3.14159265358979f / 128.0f) * ((float)f + 0.5f));
            const float tw = bk[1] + bk[1];
#pragma unroll
            for (int k = 2; k < KK; ++k) bk[k] = fmaf(tw, bk[k - 1], -bk[k - 2]);
            const float x0 = __log2f(1.0f + fabsf(v.x));
            const float x1 = __log2f(1.0f + fabsf(v.y));
            const float x2 = __log2f(1.0f + fabsf(v.z));
            const float x3 = __log2f(1.0f + fabsf(v.w));
#pragma unroll
            for (int k = 0; k < KK; ++k) {
                ac[k][0] = fmaf(bk[k], x0, ac[k][0]);
                ac[k][1] = fmaf(bk[k], x1, ac[k][1]);
                ac[k][2] = fmaf(bk[k], x2, ac[k][2]);
                ac[k][3] = fmaf(bk[k], x3, ac[k][3]);
            }
        }
    };

    // prologue: fill the ring (16 loads/wave in flight)
    issue_batch(0); issue_batch(1); issue_batch(2); issue_batch(3);

    // steady state: batch b arrives when <=12 of my loads remain outstanding.
    // {vmcnt(12); barrier} -> all waves' quarters landed; compute; barrier
    // (slot free); issue b+4. vmcnt never drains to 0 here.
    for (int bt = 0; bt <= 28; ++bt) {
        wait_vm<12>();
        __builtin_amdgcn_s_barrier();
        __builtin_amdgcn_sched_barrier(0);
        compute_batch(bt);
        __builtin_amdgcn_s_barrier();
        __builtin_amdgcn_sched_barrier(0);
        if (bt < 28) issue_batch(bt + 4);
    }
    // tail: outstanding shrinks 12->8->4->0
    wait_vm<8>();
    __builtin_amdgcn_s_barrier();
    __builtin_amdgcn_sched_barrier(0);
    compute_batch(29);
    wait_vm<4>();
    __builtin_amdgcn_s_barrier();
    __builtin_amdgcn_sched_barrier(0);
    compute_batch(30);
    wait_vm<0>();
    __builtin_amdgcn_s_barrier();
    __builtin_amdgcn_sched_barrier(0);
    compute_batch(31);

    // cache unscaled cepstra: float4 per thread per plane, 4KB/wave coalesced
    const size_t col0 = (size_t)b * TT + t0 + tid * CPT;
#pragma unroll
    for (int k = 0; k < KK; ++k)
        *(float4*)&dst[(size_t)k * NT + col0] =
            make_float4(ac[k][0], ac[k][1], ac[k][2], ac[k][3]);

    // stats: per-k sum & sumsq over this block's 1024 columns (each counted once)
#pragma unroll
    for (int k = 0; k < KK; ++k) {
        float s = (ac[k][0] + ac[k][1]) + (ac[k][2] + ac[k][3]);
        float q = fmaf(ac[k][0], ac[k][0], ac[k][1] * ac[k][1]) +
                  fmaf(ac[k][2], ac[k][2], ac[k][3] * ac[k][3]);
        s = wave_sum(s);
        q = wave_sum(q);
        if (lane == 63) { red[wave][k] = s; red[wave][13 + k] = q; }
    }
    __syncthreads();
    if (tid < 26) {
        const float v = red[0][tid] + red[1][tid] + red[2][tid] + red[3][tid];
        atomicAdd(&sums[(tensor * 26 + tid) * 16], v);   // own 64B line
    }
}

// Pass 2: finalize mean / 1/(std+1e-6) (ddof=1) in LDS, stream cached
// cepstra (27 MB, L3-hot), per-column mcd, block sum -> atomicAdd(out).
__global__ __launch_bounds__(256) void pass2_kernel(
    const float* __restrict__ sums, const float* __restrict__ cT,
    const float* __restrict__ cP, float* __restrict__ out)
{
    __shared__ float mS[2][13], iS[2][13];
    if (threadIdx.x < 26) {
        const int tns = threadIdx.x >= 13;
        const int k   = threadIdx.x - tns * 13;
        const float s = sums[(tns * 26 + k) * 16];
        const float q = sums[(tns * 26 + 13 + k) * 16];
        const float N = (float)NT;
        const float m = s / N;
        const float var = fmaxf((q - s * m) / (N - 1.0f), 0.0f);
        mS[tns][k] = m;
        iS[tns][k] = 1.0f / (sqrtf(var) + 1e-6f);
    }
    __syncthreads();

    const int col = blockIdx.x * 256 + threadIdx.x;   // [0, NT)
    float ss = 0.0f;
#pragma unroll
    for (int k = 0; k < KK; ++k) {
        const float a = cT[(size_t)k * NT + col];
        const float p = cP[(size_t)k * NT + col];
        const float d = (a - mS[0][k]) * iS[0][k] - (p - mS[1][k]) * iS[1][k];
        ss = fmaf(d, d, ss);
    }
    float v = wave_sum(MCD_C * sqrtf(ss));

    const int lane = threadIdx.x & 63;
    const int wave = threadIdx.x >> 6;
    __shared__ float r2[4];
    if (lane == 63) r2[wave] = v;
    __syncthreads();
    if (threadIdx.x == 0)
        atomicAdd(out, (r2[0] + r2[1] + r2[2] + r2[3]) * (1.0f / (float)NT));
}

extern "C" void kernel_launch(void* const* d_in, const int* in_sizes, int n_in,
                              void* d_out, int out_size, void* d_ws, size_t ws_size,
                              hipStream_t stream) {
    const float* melT = (const float*)d_in[0];
    const float* melP = (const float*)d_in[1];
    float* out  = (float*)d_out;
    float* sums = (float*)d_ws;                     // padded stats
    float* cT   = (float*)((char*)d_ws + 8192);     // 13*NT floats
    float* cP   = cT + (size_t)KK * NT;             // 13*NT floats

    hipMemsetAsync(d_ws, 0, 4096, stream);          // zero stat accumulators
    hipMemsetAsync(d_out, 0, sizeof(float), stream);// out accumulates atomically

    pass1_kernel<<<512, 256, 0, stream>>>(melT, melP, sums, cT, cP);
    pass2_kernel<<<1024, 256, 0, stream>>>(sums, cT, cP, out);
}